// Round 16
// baseline (155.384 us; speedup 1.0000x reference)
//
#include <hip/hip_runtime.h>

typedef unsigned short u16;
typedef __attribute__((ext_vector_type(4))) float f32x4;
typedef __attribute__((ext_vector_type(8))) short bf16x8;
typedef __attribute__((ext_vector_type(4))) short bf16x4;
typedef __attribute__((ext_vector_type(4))) unsigned short u16x4;
typedef __attribute__((ext_vector_type(2))) unsigned short u16x2;

#define DEV __device__ __forceinline__

DEV float bf2f(u16 u){ unsigned x = ((unsigned)u) << 16; return __builtin_bit_cast(float, x); }
DEV u16 f2bf(float f){
  unsigned x = __builtin_bit_cast(unsigned, f);
  x += 0x7fffu + ((x >> 16) & 1u);
  return (u16)(x >> 16);
}
// pack {lo,hi} f32 -> two bf16 (truncation) in one v_perm_b32
DEV unsigned pack_bf16_trunc(float lo, float hi){
  return __builtin_amdgcn_perm(__builtin_bit_cast(unsigned, hi),
                               __builtin_bit_cast(unsigned, lo), 0x07060302u);
}

DEV void gload_lds16(const void* g, void* l){
  __builtin_amdgcn_global_load_lds(
      (const __attribute__((address_space(1))) unsigned int*)(unsigned long long)g,
      (__attribute__((address_space(3))) unsigned int*)(unsigned)(unsigned long long)l,
      16, 0, 0);
}

// ---------------- pack x: f32 -> bf16, row-major [4096][2048] ----------------
__global__ void __launch_bounds__(256) k_pack_x(const float* __restrict__ x,
                                                u16* __restrict__ xb, int n4){
  int i = blockIdx.x * 256 + threadIdx.x;
  if (i < n4){
    f32x4 v = *(const f32x4*)&x[i * 4];
    u16x4 o;
    o[0] = f2bf(v[0]); o[1] = f2bf(v[1]); o[2] = f2bf(v[2]); o[3] = f2bf(v[3]);
    *(u16x4*)&xb[i * 4] = o;
  }
}

// ------- pack weights: Wt[n][k] = W[k][n] (bf16) -------
__global__ void __launch_bounds__(256) k_pack_w(const float* __restrict__ Wq,
                                                const float* __restrict__ Wk,
                                                const float* __restrict__ Wv,
                                                u16* __restrict__ Wt){
  __shared__ u16 tile[64][72];
  const int n0 = blockIdx.x * 64, k0 = blockIdx.y * 64;
  const float* src; int ncols, nloc;
  if (n0 < 2048)      { src = Wq; ncols = 2048; nloc = n0; }
  else if (n0 < 2560) { src = Wk; ncols = 512;  nloc = n0 - 2048; }
  else                { src = Wv; ncols = 512;  nloc = n0 - 2560; }
  #pragma unroll
  for (int i = 0; i < 4; ++i){
    int e = i * 1024 + threadIdx.x * 4;
    int r = e >> 6, c = e & 63;
    f32x4 v = *(const f32x4*)&src[(size_t)(k0 + r) * ncols + nloc + c];
    u16x4 o;
    o[0] = f2bf(v[0]); o[1] = f2bf(v[1]); o[2] = f2bf(v[2]); o[3] = f2bf(v[3]);
    *(u16x4*)&tile[r][c] = o;
  }
  __syncthreads();
  #pragma unroll
  for (int i = 0; i < 4; ++i){
    int e = i * 1024 + threadIdx.x * 4;
    int rn = e >> 6, ck = e & 63;
    u16x4 o;
    o[0] = tile[ck + 0][rn]; o[1] = tile[ck + 1][rn];
    o[2] = tile[ck + 2][rn]; o[3] = tile[ck + 3][rn];
    *(u16x4*)&Wt[(size_t)(n0 + rn) * 2048 + k0 + ck] = o;
  }
}

// ---------------- RoPE tables: [2048][32] f32 each ----------------
__global__ void __launch_bounds__(256) k_tables(float* __restrict__ cosT,
                                                float* __restrict__ sinT){
  int i = blockIdx.x * 256 + threadIdx.x;  // 65536
  int pos = i >> 5, f = i & 31;
  float freq = expf(-(float)f * 0.28782313662425574f);  // 10000^(-f/32)
  float a = (float)pos * freq;
  cosT[i] = cosf(a);
  sinT[i] = sinf(a);
}

// ---- GEMM, split-K=2, DOUBLE-BUFFERED (attn-proven 1-barrier/iter loop). ----
// 128x128 tile, BK=32, 2x16KB LDS. blockIdx.z = K-half; partial bf16 z=0->P0, z=1->P1.
// LDS XOR-swizzled both-sides: chunk ^= (row&3)^((row>>2)&3).
__global__ void __launch_bounds__(256) k_gemm(const u16* __restrict__ Xb,
                                              const u16* __restrict__ Wt,
                                              u16* __restrict__ P0,
                                              u16* __restrict__ P1){
  __shared__ u16 lA[2][128 * 32];
  __shared__ u16 lB[2][128 * 32];
  const int tid = threadIdx.x;
  const int wid = tid >> 6, lane = tid & 63;
  const int g = lane >> 4, lr = lane & 15;
  const int m0 = blockIdx.x * 128, n0 = blockIdx.y * 128;
  const int z = blockIdx.z;
  const int wm = wid >> 1, wn = wid & 1;

  f32x4 acc[4][4];
  #pragma unroll
  for (int i = 0; i < 4; ++i)
    #pragma unroll
    for (int j = 0; j < 4; ++j) acc[i][j] = (f32x4){0.f, 0.f, 0.f, 0.f};

  const char* gA = (const char*)Xb + (size_t)m0 * 4096 + z * 2048;  // K-half offset
  const char* gB = (const char*)Wt + (size_t)n0 * 4096 + z * 2048;

  auto STAGE = [&](int kt, int bb){
    const int k0b = kt * 64;                     // 32 bf16 = 64B per row-window
    #pragma unroll
    for (int i = 0; i < 2; ++i){
      int idx = i * 256 + tid;                   // 512 chunks of 16B per matrix
      int row = idx >> 2, cc = idx & 3;
      int sc = cc ^ (row & 3) ^ ((row >> 2) & 3);  // pre-swizzled source chunk
      gload_lds16(gA + (size_t)row * 4096 + k0b + sc * 16,
                  (char*)&lA[bb][0] + i * 4096 + wid * 1024);
      gload_lds16(gB + (size_t)row * 4096 + k0b + sc * 16,
                  (char*)&lB[bb][0] + i * 4096 + wid * 1024);
    }
  };

  int buf = 0;
  STAGE(0, 0);

  for (int kt = 0; kt < 32; ++kt){
    __syncthreads();                   // drains prefetch (latency hidden under prior compute)
    if (kt + 1 < 32) STAGE(kt + 1, buf ^ 1);

    bf16x8 a[4], b[4];
    #pragma unroll
    for (int i = 0; i < 4; ++i){
      int rowA = wm * 64 + i * 16 + lr;
      int ch = g ^ (rowA & 3) ^ ((rowA >> 2) & 3);
      a[i] = *(const bf16x8*)&lA[buf][rowA * 32 + ch * 8];
    }
    #pragma unroll
    for (int j = 0; j < 4; ++j){
      int rowB = wn * 64 + j * 16 + lr;
      int ch = g ^ (rowB & 3) ^ ((rowB >> 2) & 3);
      b[j] = *(const bf16x8*)&lB[buf][rowB * 32 + ch * 8];
    }
    #pragma unroll
    for (int i = 0; i < 4; ++i)
      #pragma unroll
      for (int j = 0; j < 4; ++j)
        acc[i][j] = __builtin_amdgcn_mfma_f32_16x16x32_bf16(a[i], b[j], acc[i][j], 0, 0, 0);

    buf ^= 1;
  }

  u16* P = z ? P1 : P0;
  #pragma unroll
  for (int i = 0; i < 4; ++i)
    #pragma unroll
    for (int j = 0; j < 4; ++j){
      int row = m0 + wm * 64 + i * 16 + g * 4;
      int col = n0 + wn * 64 + j * 16 + lr;
      #pragma unroll
      for (int r = 0; r < 4; ++r)
        P[(size_t)(row + r) * 3072 + col] = f2bf(acc[i][j][r]);
    }
}

// ---- reduce partials + epilogue: Q -> P0 in-place; K -> RoPE -> Kr; V -> transpose -> Vt ----
// grid (48 col-tiles, 64 row-tiles), 64x64 tile per block, 256 threads.
__global__ void __launch_bounds__(256) k_reduce(u16* __restrict__ P0,
                                                const u16* __restrict__ P1,
                                                const float* __restrict__ cosT,
                                                const float* __restrict__ sinT,
                                                u16* __restrict__ Kr,
                                                u16* __restrict__ Vt){
  __shared__ u16 tile[64][72];
  const int col0 = blockIdx.x * 64, row0 = blockIdx.y * 64;
  const int b = row0 >> 11, s0 = row0 & 2047;

  if (col0 < 2048){
    // ---- Q: sum -> P0 in place ----
    #pragma unroll
    for (int p = 0; p < 2; ++p){
      int it = p * 256 + threadIdx.x;
      int r = it >> 3, ch = it & 7;
      size_t off = (size_t)(row0 + r) * 3072 + col0 + ch * 8;
      bf16x8 a = *(const bf16x8*)&P0[off];
      bf16x8 c = *(const bf16x8*)&P1[off];
      bf16x8 o;
      #pragma unroll
      for (int j = 0; j < 8; ++j)
        o[j] = (short)f2bf(bf2f((u16)a[j]) + bf2f((u16)c[j]));
      *(bf16x8*)&P0[off] = o;
    }
  } else if (col0 < 2560){
    // ---- K: sum + RoPE -> Kr[b][hk][s][64] ----
    const int hk = (col0 - 2048) >> 6;
    u16* kout = Kr + (size_t)(b * 8 + hk) * 2048 * 64;
    #pragma unroll
    for (int p = 0; p < 2; ++p){
      int it = p * 256 + threadIdx.x;
      int r = it >> 3, ch = it & 7;
      int s = s0 + r;
      size_t off = (size_t)(row0 + r) * 3072 + col0 + ch * 8;
      bf16x8 a = *(const bf16x8*)&P0[off];
      bf16x8 c = *(const bf16x8*)&P1[off];
      float v[8];
      #pragma unroll
      for (int j = 0; j < 8; ++j) v[j] = bf2f((u16)a[j]) + bf2f((u16)c[j]);
      u16x4 o0, o1;
      #pragma unroll
      for (int j2 = 0; j2 < 4; ++j2){
        int fi = ch * 4 + j2;
        float cs = cosT[s * 32 + fi], sn = sinT[s * 32 + fi];
        float xe = v[2 * j2], xo = v[2 * j2 + 1];
        float oe = xe * cs - xo * sn;
        float oo = xe * sn + xo * cs;
        if (j2 < 2){ o0[2 * j2] = f2bf(oe); o0[2 * j2 + 1] = f2bf(oo); }
        else       { o1[2 * (j2 - 2)] = f2bf(oe); o1[2 * (j2 - 2) + 1] = f2bf(oo); }
      }
      *(u16x4*)&kout[(size_t)s * 64 + ch * 8] = o0;
      *(u16x4*)&kout[(size_t)s * 64 + ch * 8 + 4] = o1;
    }
  } else {
    // ---- V: sum -> LDS -> transposed -> Vt[b][hk][d][s] ----
    const int hk = (col0 - 2560) >> 6;
    #pragma unroll
    for (int p = 0; p < 2; ++p){
      int it = p * 256 + threadIdx.x;
      int r = it >> 3, ch = it & 7;
      size_t off = (size_t)(row0 + r) * 3072 + col0 + ch * 8;
      bf16x8 a = *(const bf16x8*)&P0[off];
      bf16x8 c = *(const bf16x8*)&P1[off];
      u16x4 t0, t1;
      #pragma unroll
      for (int j = 0; j < 4; ++j){
        t0[j] = f2bf(bf2f((u16)a[j]) + bf2f((u16)c[j]));
        t1[j] = f2bf(bf2f((u16)a[j + 4]) + bf2f((u16)c[j + 4]));
      }
      *(u16x4*)&tile[r][ch * 8] = t0;
      *(u16x4*)&tile[r][ch * 8 + 4] = t1;
    }
    __syncthreads();
    #pragma unroll
    for (int i = 0; i < 4; ++i){
      int e = i * 1024 + threadIdx.x * 4;
      int d = e >> 6, sc = e & 63;
      u16x4 o;
      o[0] = tile[sc + 0][d]; o[1] = tile[sc + 1][d];
      o[2] = tile[sc + 2][d]; o[3] = tile[sc + 3][d];
      *(u16x4*)&Vt[((size_t)(b * 8 + hk) * 64 + d) * 2048 + s0 + sc] = o;
    }
  }
}

// ---------------- Flash attention: causal GQA, KVBLK=64, qt-PAIRED uniform blocks ----------------
// R15-proven: 8 waves/block (512 thr), 2 heads/block, two passes qt = bx / 31-bx
// -> every block exactly 33 tile-units. Grid (16,16,2) = 512 blocks = 2/CU.
// Max-free softmax + deferred per-lane lsum; v_perm P-pack.
// Quarantined intrinsics (NaN, R3/R4/R6): exp2f builtin, cvt_pk asm, setprio.
__global__ void __launch_bounds__(512) k_attn(const u16* __restrict__ C,
                                              const u16* __restrict__ Kr,
                                              const u16* __restrict__ Vt,
                                              const float* __restrict__ cosT,
                                              const float* __restrict__ sinT,
                                              float* __restrict__ out){
  __shared__ u16 lK[2][4096];
  __shared__ u16 lV[2][4096];

  const int bx = (int)blockIdx.x;       // 0..15 -> qt pair {bx, 31-bx}
  const int by = (int)blockIdx.y;       // 0..15 -> hk = by>>1, head-pair = by&1
  const int b = (int)blockIdx.z;
  const int tid = threadIdx.x;
  const int wid = tid >> 6, lane = tid & 63;
  const int g = lane >> 4, lr = lane & 15;
  const int hk = by >> 1;
  const int hq = hk * 4 + (by & 1) * 2 + (wid >> 2);
  const float QSCL = 0.125f;            // fold 1/sqrt(64) into Q
  const float NEG = -60000.0f;          // masked-score sentinel (exp -> exact 0)
  const int sw = lr & 7;

  const char* kgbase = (const char*)(Kr + (size_t)(b * 8 + hk) * 2048 * 64);
  const char* vgbase = (const char*)(Vt + (size_t)(b * 8 + hk) * 64 * 2048);

  // STAGE tile tt: waves 0-3 stage K (512 chunks, 2/lane), waves 4-7 stage V.
  auto STAGE = [&](int tt, int bb){
    if (wid < 4){
      const char* kg = kgbase + (size_t)tt * 8192;     // 64 rows x 128B contiguous
      #pragma unroll
      for (int i = 0; i < 2; ++i){
        int dc = wid * 128 + i * 64 + lane;
        int row = dc >> 3, cc = dc & 7;
        int sc = cc ^ (row & 7);
        gload_lds16(kg + row * 128 + sc * 16,
                    (char*)&lK[bb][0] + wid * 2048 + i * 1024);
      }
    } else {
      const char* vg = vgbase + (size_t)tt * 128;      // 64B-window rows, 4096B stride
      int w2 = wid - 4;
      #pragma unroll
      for (int i = 0; i < 2; ++i){
        int dc = w2 * 128 + i * 64 + lane;
        int row = dc >> 3, cc = dc & 7;
        int sc = cc ^ (row & 7);
        gload_lds16(vg + (size_t)row * 4096 + sc * 16,
                    (char*)&lV[bb][0] + w2 * 2048 + i * 1024);
      }
    }
  };

  #pragma unroll 1
  for (int pass = 0; pass < 2; ++pass){
    const int qt = pass ? 31 - bx : bx;
    const int q16 = qt * 64 + (wid & 3) * 16;
    const int qrow = q16 + lr;

    // Q fragments (B-operand of 16x16x32: B[k=d][col=q]), RoPE + scale in-register
    bf16x8 qf[2];
    {
      const u16* qsrc = C + (size_t)(b * 2048 + qrow) * 3072 + hq * 64;
      #pragma unroll
      for (int c = 0; c < 2; ++c){
        bf16x8 v = *(const bf16x8*)&qsrc[c * 32 + g * 8];
        int i0 = c * 16 + g * 4;
        f32x4 cs = *(const f32x4*)&cosT[qrow * 32 + i0];
        f32x4 sn = *(const f32x4*)&sinT[qrow * 32 + i0];
        bf16x8 o;
        #pragma unroll
        for (int t = 0; t < 4; ++t){
          float xe = bf2f((u16)v[2 * t]), xo = bf2f((u16)v[2 * t + 1]);
          o[2 * t]     = (short)f2bf((xe * cs[t] - xo * sn[t]) * QSCL);
          o[2 * t + 1] = (short)f2bf((xe * sn[t] + xo * cs[t]) * QSCL);
        }
        qf[c] = o;
      }
    }

    f32x4 oacc[4];
    #pragma unroll
    for (int dt = 0; dt < 4; ++dt) oacc[dt] = (f32x4){0.f, 0.f, 0.f, 0.f};
    float lsum = 0.0f;                  // per-lane partial; reduced once at end

    __syncthreads();                    // protect LDS reuse across passes
    int buf = 0;
    STAGE(0, 0);

    // ============ hot loop: fully-unmasked tiles t = 0..qt-1 ============
    for (int t = 0; t < qt; ++t){
      __syncthreads();
      STAGE(t + 1, buf ^ 1);

      const char* lKb = (const char*)&lK[buf][0];
      const char* lVb = (const char*)&lV[buf][0];

      // ---- QK^T: S^T[kv][q], all 4 subtiles unmasked ----
      f32x4 st[4];
      #pragma unroll
      for (int ks = 0; ks < 4; ++ks){
        st[ks] = (f32x4){0.f, 0.f, 0.f, 0.f};
        int row = ks * 16 + lr;
        bf16x8 k0 = *(const bf16x8*)(lKb + row * 128 + ((0 + g) ^ sw) * 16);
        bf16x8 k1 = *(const bf16x8*)(lKb + row * 128 + ((4 + g) ^ sw) * 16);
        st[ks] = __builtin_amdgcn_mfma_f32_16x16x32_bf16(k0, qf[0], st[ks], 0, 0, 0);
        st[ks] = __builtin_amdgcn_mfma_f32_16x16x32_bf16(k1, qf[1], st[ks], 0, 0, 0);
      }

      // ---- max-free softmax: p = exp(s), per-lane lsum ----
      float p[4][4];
      #pragma unroll
      for (int ks = 0; ks < 4; ++ks){
        #pragma unroll
        for (int r = 0; r < 4; ++r){
          float e = __expf(st[ks][r]);
          p[ks][r] = e; lsum += e;
        }
      }

      // ---- PV: A[row=q=lr][k=kv=4g+j] = p, B from V^T LDS tile ----
      #pragma unroll
      for (int ks = 0; ks < 4; ++ks){
        union { unsigned u[2]; bf16x4 v; } pu;
        pu.u[0] = pack_bf16_trunc(p[ks][0], p[ks][1]);
        pu.u[1] = pack_bf16_trunc(p[ks][2], p[ks][3]);
        bf16x4 pa = pu.v;
        int chunk = ks * 2 + (g >> 1);
        #pragma unroll
        for (int dt = 0; dt < 4; ++dt){
          int row = dt * 16 + lr;
          bf16x4 vb = *(const bf16x4*)(lVb + row * 128 + (chunk ^ sw) * 16 + (g & 1) * 8);
          oacc[dt] = __builtin_amdgcn_mfma_f32_16x16x16bf16_1k(pa, vb, oacc[dt], 0, 0, 0);
        }
      }

      buf ^= 1;
    }

    // ============ diag tile t = qt (masked epilogue) ============
    {
      __syncthreads();
      const char* lKb = (const char*)&lK[buf][0];
      const char* lVb = (const char*)&lV[buf][0];
      const int ksmax = wid & 3;

      f32x4 st[4];
      #pragma unroll
      for (int ks = 0; ks < 4; ++ks){
        st[ks] = (f32x4){0.f, 0.f, 0.f, 0.f};
        if (ks <= ksmax){
          int row = ks * 16 + lr;
          bf16x8 k0 = *(const bf16x8*)(lKb + row * 128 + ((0 + g) ^ sw) * 16);
          bf16x8 k1 = *(const bf16x8*)(lKb + row * 128 + ((4 + g) ^ sw) * 16);
          st[ks] = __builtin_amdgcn_mfma_f32_16x16x32_bf16(k0, qf[0], st[ks], 0, 0, 0);
          st[ks] = __builtin_amdgcn_mfma_f32_16x16x32_bf16(k1, qf[1], st[ks], 0, 0, 0);
        }
      }

      #pragma unroll
      for (int ks = 0; ks < 4; ++ks){
        if (ks <= ksmax){
          float p[4];
          #pragma unroll
          for (int r = 0; r < 4; ++r){
            float v = st[ks][r];
            if (ks == ksmax && (4 * g + r > lr)) v = NEG;   // exp -> exact 0
            float e = __expf(v);
            p[r] = e; lsum += e;
          }
          union { unsigned u[2]; bf16x4 v; } pu;
          pu.u[0] = pack_bf16_trunc(p[0], p[1]);
          pu.u[1] = pack_bf16_trunc(p[2], p[3]);
          bf16x4 pa = pu.v;
          int chunk = ks * 2 + (g >> 1);
          #pragma unroll
          for (int dt = 0; dt < 4; ++dt){
            int row = dt * 16 + lr;
            bf16x4 vb = *(const bf16x4*)(lVb + row * 128 + (chunk ^ sw) * 16 + (g & 1) * 8);
            oacc[dt] = __builtin_amdgcn_mfma_f32_16x16x16bf16_1k(pa, vb, oacc[dt], 0, 0, 0);
          }
        }
      }
    }

    // ---- pass final: one cross-lane lsum reduce, normalize, write ----
    lsum += __shfl_xor(lsum, 16);
    lsum += __shfl_xor(lsum, 32);
    float inv[4];
    #pragma unroll
    for (int r = 0; r < 4; ++r) inv[r] = 1.0f / __shfl(lsum, 4 * g + r);
    float* obase = out + (size_t)(b * 2048 + q16) * 2048 + hq * 64;
    #pragma unroll
    for (int dt = 0; dt < 4; ++dt)
      #pragma unroll
      for (int r = 0; r < 4; ++r)
        obase[(size_t)(4 * g + r) * 2048 + dt * 16 + lr] = oacc[dt][r] * inv[r];
  }
}

// ---------------- launch ----------------
extern "C" void kernel_launch(void* const* d_in, const int* in_sizes, int n_in,
                              void* d_out, int out_size, void* d_ws, size_t ws_size,
                              hipStream_t stream) {
  const float* x  = (const float*)d_in[0];
  const float* Wq = (const float*)d_in[1];
  const float* Wk = (const float*)d_in[2];
  const float* Wv = (const float*)d_in[3];
  float* out = (float*)d_out;
  char* ws = (char*)d_ws;

  u16* Xb   = (u16*)(ws + 0);            // 16,777,216
  u16* Wt   = (u16*)(ws + 16777216);     // 12,582,912
  u16* Cb   = (u16*)(ws + 29360128);     // 25,165,824  (P0; Q cols final here)
  u16* Kr   = (u16*)(ws + 54525952);     //  4,194,304
  u16* Vt   = (u16*)(ws + 58720256);     //  4,194,304
  float* cosT = (float*)(ws + 62914560); //    262,144
  float* sinT = (float*)(ws + 63176704); //    262,144
  u16* P1   = (u16*)d_out;               // 25,165,824 <= 33,554,432 (attn overwrites after)

  k_pack_x<<<8192, 256, 0, stream>>>(x, Xb, 2097152);
  k_pack_w<<<dim3(48, 32), 256, 0, stream>>>(Wq, Wk, Wv, Wt);
  k_tables<<<256, 256, 0, stream>>>(cosT, sinT);
  k_gemm<<<dim3(32, 24, 2), 256, 0, stream>>>(Xb, Wt, Cb, P1);
  k_reduce<<<dim3(48, 64), 256, 0, stream>>>(Cb, P1, cosT, sinT, Kr, Vt);
  k_attn<<<dim3(16, 16, 2), 512, 0, stream>>>(Cb, Kr, Vt, cosT, sinT, out);
}

// Round 17
// 142.786 us; speedup vs baseline: 1.0882x; 1.0882x over previous
//
#include <hip/hip_runtime.h>

typedef unsigned short u16;
typedef __attribute__((ext_vector_type(4))) float f32x4;
typedef __attribute__((ext_vector_type(8))) short bf16x8;
typedef __attribute__((ext_vector_type(4))) short bf16x4;
typedef __attribute__((ext_vector_type(4))) unsigned short u16x4;
typedef __attribute__((ext_vector_type(2))) unsigned short u16x2;

#define DEV __device__ __forceinline__

DEV float bf2f(u16 u){ unsigned x = ((unsigned)u) << 16; return __builtin_bit_cast(float, x); }
DEV u16 f2bf(float f){
  unsigned x = __builtin_bit_cast(unsigned, f);
  x += 0x7fffu + ((x >> 16) & 1u);
  return (u16)(x >> 16);
}
// pack {lo,hi} f32 -> two bf16 (truncation) in one v_perm_b32
DEV unsigned pack_bf16_trunc(float lo, float hi){
  return __builtin_amdgcn_perm(__builtin_bit_cast(unsigned, hi),
                               __builtin_bit_cast(unsigned, lo), 0x07060302u);
}

DEV void gload_lds16(const void* g, void* l){
  __builtin_amdgcn_global_load_lds(
      (const __attribute__((address_space(1))) unsigned int*)(unsigned long long)g,
      (__attribute__((address_space(3))) unsigned int*)(unsigned)(unsigned long long)l,
      16, 0, 0);
}

// ---- merged prep: [0,8192) pack x; [8192,9728) pack W; [9728,9984) RoPE tables ----
__global__ void __launch_bounds__(256) k_prep(const float* __restrict__ x,
                                              const float* __restrict__ Wq,
                                              const float* __restrict__ Wk,
                                              const float* __restrict__ Wv,
                                              u16* __restrict__ xb,
                                              u16* __restrict__ Wt,
                                              float* __restrict__ cosT,
                                              float* __restrict__ sinT){
  __shared__ u16 tile[64][72];
  const int id = (int)blockIdx.x;
  if (id < 8192){
    int i = id * 256 + threadIdx.x;          // < 2097152
    f32x4 v = *(const f32x4*)&x[(size_t)i * 4];
    u16x4 o;
    o[0] = f2bf(v[0]); o[1] = f2bf(v[1]); o[2] = f2bf(v[2]); o[3] = f2bf(v[3]);
    *(u16x4*)&xb[(size_t)i * 4] = o;
  } else if (id < 9728){
    int idx = id - 8192;                     // 0..1535
    const int n0 = (idx % 48) * 64, k0 = (idx / 48) * 64;
    const float* src; int ncols, nloc;
    if (n0 < 2048)      { src = Wq; ncols = 2048; nloc = n0; }
    else if (n0 < 2560) { src = Wk; ncols = 512;  nloc = n0 - 2048; }
    else                { src = Wv; ncols = 512;  nloc = n0 - 2560; }
    #pragma unroll
    for (int i = 0; i < 4; ++i){
      int e = i * 1024 + threadIdx.x * 4;
      int r = e >> 6, c = e & 63;
      f32x4 v = *(const f32x4*)&src[(size_t)(k0 + r) * ncols + nloc + c];
      u16x4 o;
      o[0] = f2bf(v[0]); o[1] = f2bf(v[1]); o[2] = f2bf(v[2]); o[3] = f2bf(v[3]);
      *(u16x4*)&tile[r][c] = o;
    }
    __syncthreads();
    #pragma unroll
    for (int i = 0; i < 4; ++i){
      int e = i * 1024 + threadIdx.x * 4;
      int rn = e >> 6, ck = e & 63;
      u16x4 o;
      o[0] = tile[ck + 0][rn]; o[1] = tile[ck + 1][rn];
      o[2] = tile[ck + 2][rn]; o[3] = tile[ck + 3][rn];
      *(u16x4*)&Wt[(size_t)(n0 + rn) * 2048 + k0 + ck] = o;
    }
  } else {
    int i = (id - 9728) * 256 + threadIdx.x; // < 65536
    int pos = i >> 5, f = i & 31;
    float freq = expf(-(float)f * 0.28782313662425574f);  // 10000^(-f/32)
    float a = (float)pos * freq;
    cosT[i] = cosf(a);
    sinT[i] = sinf(a);
  }
}

// ---- GEMM, split-K=2, BK=64 single-buffer (R12 loop + R15 split-K). ----
// 128x128 tile, 32KB LDS, 16 iterations (half the barrier drains of BK=32).
// LDS XOR-swizzled both-sides: chunk ^= row&7. Partial bf16: z=0 -> P0, z=1 -> P1.
__global__ void __launch_bounds__(256) k_gemm(const u16* __restrict__ Xb,
                                              const u16* __restrict__ Wt,
                                              u16* __restrict__ P0,
                                              u16* __restrict__ P1){
  __shared__ u16 lA[128 * 64];
  __shared__ u16 lB[128 * 64];
  const int tid = threadIdx.x;
  const int wid = tid >> 6, lane = tid & 63;
  const int g = lane >> 4, lr = lane & 15;
  const int m0 = blockIdx.x * 128, n0 = blockIdx.y * 128;
  const int z = blockIdx.z;
  const int wm = wid >> 1, wn = wid & 1;

  f32x4 acc[4][4];
  #pragma unroll
  for (int i = 0; i < 4; ++i)
    #pragma unroll
    for (int j = 0; j < 4; ++j) acc[i][j] = (f32x4){0.f, 0.f, 0.f, 0.f};

  const char* gA = (const char*)Xb + (size_t)m0 * 4096 + z * 2048;  // K-half offset
  const char* gB = (const char*)Wt + (size_t)n0 * 4096 + z * 2048;

  for (int kt = 0; kt < 16; ++kt){
    const int k0b = kt * 128;                  // 64 bf16 = 128B per row-window
    #pragma unroll
    for (int i = 0; i < 4; ++i){
      int idx = i * 256 + tid;                 // 1024 chunks of 16B per matrix
      int row = idx >> 3, cc = idx & 7;
      int sc = cc ^ (row & 7);                 // pre-swizzled source chunk
      gload_lds16(gA + (size_t)row * 4096 + k0b + sc * 16, (char*)lA + i * 4096 + wid * 1024);
      gload_lds16(gB + (size_t)row * 4096 + k0b + sc * 16, (char*)lB + i * 4096 + wid * 1024);
    }
    __syncthreads();
    #pragma unroll
    for (int kk = 0; kk < 2; ++kk){
      bf16x8 a[4], b[4];
      #pragma unroll
      for (int i = 0; i < 4; ++i){
        int rowA = wm * 64 + i * 16 + lr;
        a[i] = *(const bf16x8*)&lA[rowA * 64 + (((kk << 2) | g) ^ (rowA & 7)) * 8];
      }
      #pragma unroll
      for (int j = 0; j < 4; ++j){
        int rowB = wn * 64 + j * 16 + lr;
        b[j] = *(const bf16x8*)&lB[rowB * 64 + (((kk << 2) | g) ^ (rowB & 7)) * 8];
      }
      #pragma unroll
      for (int i = 0; i < 4; ++i)
        #pragma unroll
        for (int j = 0; j < 4; ++j)
          acc[i][j] = __builtin_amdgcn_mfma_f32_16x16x32_bf16(a[i], b[j], acc[i][j], 0, 0, 0);
    }
    __syncthreads();
  }

  u16* P = z ? P1 : P0;
  #pragma unroll
  for (int i = 0; i < 4; ++i)
    #pragma unroll
    for (int j = 0; j < 4; ++j){
      int row = m0 + wm * 64 + i * 16 + g * 4;
      int col = n0 + wn * 64 + j * 16 + lr;
      #pragma unroll
      for (int r = 0; r < 4; ++r)
        P[(size_t)(row + r) * 3072 + col] = f2bf(acc[i][j][r]);
    }
}

// ---- reduce partials + epilogue: Q -> P0 in-place; K -> RoPE -> Kr; V -> transpose -> Vt ----
// grid (48 col-tiles, 64 row-tiles), 64x64 tile per block, 256 threads.
__global__ void __launch_bounds__(256) k_reduce(u16* __restrict__ P0,
                                                const u16* __restrict__ P1,
                                                const float* __restrict__ cosT,
                                                const float* __restrict__ sinT,
                                                u16* __restrict__ Kr,
                                                u16* __restrict__ Vt){
  __shared__ u16 tile[64][72];
  const int col0 = blockIdx.x * 64, row0 = blockIdx.y * 64;
  const int b = row0 >> 11, s0 = row0 & 2047;

  if (col0 < 2048){
    // ---- Q: sum -> P0 in place ----
    #pragma unroll
    for (int p = 0; p < 2; ++p){
      int it = p * 256 + threadIdx.x;
      int r = it >> 3, ch = it & 7;
      size_t off = (size_t)(row0 + r) * 3072 + col0 + ch * 8;
      bf16x8 a = *(const bf16x8*)&P0[off];
      bf16x8 c = *(const bf16x8*)&P1[off];
      bf16x8 o;
      #pragma unroll
      for (int j = 0; j < 8; ++j)
        o[j] = (short)f2bf(bf2f((u16)a[j]) + bf2f((u16)c[j]));
      *(bf16x8*)&P0[off] = o;
    }
  } else if (col0 < 2560){
    // ---- K: sum + RoPE -> Kr[b][hk][s][64] ----
    const int hk = (col0 - 2048) >> 6;
    u16* kout = Kr + (size_t)(b * 8 + hk) * 2048 * 64;
    #pragma unroll
    for (int p = 0; p < 2; ++p){
      int it = p * 256 + threadIdx.x;
      int r = it >> 3, ch = it & 7;
      int s = s0 + r;
      size_t off = (size_t)(row0 + r) * 3072 + col0 + ch * 8;
      bf16x8 a = *(const bf16x8*)&P0[off];
      bf16x8 c = *(const bf16x8*)&P1[off];
      float v[8];
      #pragma unroll
      for (int j = 0; j < 8; ++j) v[j] = bf2f((u16)a[j]) + bf2f((u16)c[j]);
      u16x4 o0, o1;
      #pragma unroll
      for (int j2 = 0; j2 < 4; ++j2){
        int fi = ch * 4 + j2;
        float cs = cosT[s * 32 + fi], sn = sinT[s * 32 + fi];
        float xe = v[2 * j2], xo = v[2 * j2 + 1];
        float oe = xe * cs - xo * sn;
        float oo = xe * sn + xo * cs;
        if (j2 < 2){ o0[2 * j2] = f2bf(oe); o0[2 * j2 + 1] = f2bf(oo); }
        else       { o1[2 * (j2 - 2)] = f2bf(oe); o1[2 * (j2 - 2) + 1] = f2bf(oo); }
      }
      *(u16x4*)&kout[(size_t)s * 64 + ch * 8] = o0;
      *(u16x4*)&kout[(size_t)s * 64 + ch * 8 + 4] = o1;
    }
  } else {
    // ---- V: sum -> LDS -> transposed -> Vt[b][hk][d][s] ----
    const int hk = (col0 - 2560) >> 6;
    #pragma unroll
    for (int p = 0; p < 2; ++p){
      int it = p * 256 + threadIdx.x;
      int r = it >> 3, ch = it & 7;
      size_t off = (size_t)(row0 + r) * 3072 + col0 + ch * 8;
      bf16x8 a = *(const bf16x8*)&P0[off];
      bf16x8 c = *(const bf16x8*)&P1[off];
      u16x4 t0, t1;
      #pragma unroll
      for (int j = 0; j < 4; ++j){
        t0[j] = f2bf(bf2f((u16)a[j]) + bf2f((u16)c[j]));
        t1[j] = f2bf(bf2f((u16)a[j + 4]) + bf2f((u16)c[j + 4]));
      }
      *(u16x4*)&tile[r][ch * 8] = t0;
      *(u16x4*)&tile[r][ch * 8 + 4] = t1;
    }
    __syncthreads();
    #pragma unroll
    for (int i = 0; i < 4; ++i){
      int e = i * 1024 + threadIdx.x * 4;
      int d = e >> 6, sc = e & 63;
      u16x4 o;
      o[0] = tile[sc + 0][d]; o[1] = tile[sc + 1][d];
      o[2] = tile[sc + 2][d]; o[3] = tile[sc + 3][d];
      *(u16x4*)&Vt[((size_t)(b * 8 + hk) * 64 + d) * 2048 + s0 + sc] = o;
    }
  }
}

// ---------------- Flash attention: causal GQA, KVBLK=64, qt-PAIRED uniform blocks ----------------
// R15-proven: 8 waves/block (512 thr), 2 heads/block, two passes qt = bx / 31-bx
// -> every block exactly 33 tile-units. Grid (16,16,2) = 512 blocks = 2/CU.
// Max-free softmax + deferred per-lane lsum; v_perm P-pack.
// Quarantined intrinsics (NaN, R3/R4/R6): exp2f builtin, cvt_pk asm, setprio.
__global__ void __launch_bounds__(512) k_attn(const u16* __restrict__ C,
                                              const u16* __restrict__ Kr,
                                              const u16* __restrict__ Vt,
                                              const float* __restrict__ cosT,
                                              const float* __restrict__ sinT,
                                              float* __restrict__ out){
  __shared__ u16 lK[2][4096];
  __shared__ u16 lV[2][4096];

  const int bx = (int)blockIdx.x;       // 0..15 -> qt pair {bx, 31-bx}
  const int by = (int)blockIdx.y;       // 0..15 -> hk = by>>1, head-pair = by&1
  const int b = (int)blockIdx.z;
  const int tid = threadIdx.x;
  const int wid = tid >> 6, lane = tid & 63;
  const int g = lane >> 4, lr = lane & 15;
  const int hk = by >> 1;
  const int hq = hk * 4 + (by & 1) * 2 + (wid >> 2);
  const float QSCL = 0.125f;            // fold 1/sqrt(64) into Q
  const float NEG = -60000.0f;          // masked-score sentinel (exp -> exact 0)
  const int sw = lr & 7;

  const char* kgbase = (const char*)(Kr + (size_t)(b * 8 + hk) * 2048 * 64);
  const char* vgbase = (const char*)(Vt + (size_t)(b * 8 + hk) * 64 * 2048);

  // STAGE tile tt: waves 0-3 stage K (512 chunks, 2/lane), waves 4-7 stage V.
  auto STAGE = [&](int tt, int bb){
    if (wid < 4){
      const char* kg = kgbase + (size_t)tt * 8192;     // 64 rows x 128B contiguous
      #pragma unroll
      for (int i = 0; i < 2; ++i){
        int dc = wid * 128 + i * 64 + lane;
        int row = dc >> 3, cc = dc & 7;
        int sc = cc ^ (row & 7);
        gload_lds16(kg + row * 128 + sc * 16,
                    (char*)&lK[bb][0] + wid * 2048 + i * 1024);
      }
    } else {
      const char* vg = vgbase + (size_t)tt * 128;      // 64B-window rows, 4096B stride
      int w2 = wid - 4;
      #pragma unroll
      for (int i = 0; i < 2; ++i){
        int dc = w2 * 128 + i * 64 + lane;
        int row = dc >> 3, cc = dc & 7;
        int sc = cc ^ (row & 7);
        gload_lds16(vg + (size_t)row * 4096 + sc * 16,
                    (char*)&lV[bb][0] + w2 * 2048 + i * 1024);
      }
    }
  };

  #pragma unroll 1
  for (int pass = 0; pass < 2; ++pass){
    const int qt = pass ? 31 - bx : bx;
    const int q16 = qt * 64 + (wid & 3) * 16;
    const int qrow = q16 + lr;

    // Q fragments (B-operand of 16x16x32: B[k=d][col=q]), RoPE + scale in-register
    bf16x8 qf[2];
    {
      const u16* qsrc = C + (size_t)(b * 2048 + qrow) * 3072 + hq * 64;
      #pragma unroll
      for (int c = 0; c < 2; ++c){
        bf16x8 v = *(const bf16x8*)&qsrc[c * 32 + g * 8];
        int i0 = c * 16 + g * 4;
        f32x4 cs = *(const f32x4*)&cosT[qrow * 32 + i0];
        f32x4 sn = *(const f32x4*)&sinT[qrow * 32 + i0];
        bf16x8 o;
        #pragma unroll
        for (int t = 0; t < 4; ++t){
          float xe = bf2f((u16)v[2 * t]), xo = bf2f((u16)v[2 * t + 1]);
          o[2 * t]     = (short)f2bf((xe * cs[t] - xo * sn[t]) * QSCL);
          o[2 * t + 1] = (short)f2bf((xe * sn[t] + xo * cs[t]) * QSCL);
        }
        qf[c] = o;
      }
    }

    f32x4 oacc[4];
    #pragma unroll
    for (int dt = 0; dt < 4; ++dt) oacc[dt] = (f32x4){0.f, 0.f, 0.f, 0.f};
    float lsum = 0.0f;                  // per-lane partial; reduced once at end

    __syncthreads();                    // protect LDS reuse across passes
    int buf = 0;
    STAGE(0, 0);

    // ============ hot loop: fully-unmasked tiles t = 0..qt-1 ============
    for (int t = 0; t < qt; ++t){
      __syncthreads();
      STAGE(t + 1, buf ^ 1);

      const char* lKb = (const char*)&lK[buf][0];
      const char* lVb = (const char*)&lV[buf][0];

      // ---- QK^T: S^T[kv][q], all 4 subtiles unmasked ----
      f32x4 st[4];
      #pragma unroll
      for (int ks = 0; ks < 4; ++ks){
        st[ks] = (f32x4){0.f, 0.f, 0.f, 0.f};
        int row = ks * 16 + lr;
        bf16x8 k0 = *(const bf16x8*)(lKb + row * 128 + ((0 + g) ^ sw) * 16);
        bf16x8 k1 = *(const bf16x8*)(lKb + row * 128 + ((4 + g) ^ sw) * 16);
        st[ks] = __builtin_amdgcn_mfma_f32_16x16x32_bf16(k0, qf[0], st[ks], 0, 0, 0);
        st[ks] = __builtin_amdgcn_mfma_f32_16x16x32_bf16(k1, qf[1], st[ks], 0, 0, 0);
      }

      // ---- max-free softmax: p = exp(s), per-lane lsum ----
      float p[4][4];
      #pragma unroll
      for (int ks = 0; ks < 4; ++ks){
        #pragma unroll
        for (int r = 0; r < 4; ++r){
          float e = __expf(st[ks][r]);
          p[ks][r] = e; lsum += e;
        }
      }

      // ---- PV: A[row=q=lr][k=kv=4g+j] = p, B from V^T LDS tile ----
      #pragma unroll
      for (int ks = 0; ks < 4; ++ks){
        union { unsigned u[2]; bf16x4 v; } pu;
        pu.u[0] = pack_bf16_trunc(p[ks][0], p[ks][1]);
        pu.u[1] = pack_bf16_trunc(p[ks][2], p[ks][3]);
        bf16x4 pa = pu.v;
        int chunk = ks * 2 + (g >> 1);
        #pragma unroll
        for (int dt = 0; dt < 4; ++dt){
          int row = dt * 16 + lr;
          bf16x4 vb = *(const bf16x4*)(lVb + row * 128 + (chunk ^ sw) * 16 + (g & 1) * 8);
          oacc[dt] = __builtin_amdgcn_mfma_f32_16x16x16bf16_1k(pa, vb, oacc[dt], 0, 0, 0);
        }
      }

      buf ^= 1;
    }

    // ============ diag tile t = qt (masked epilogue) ============
    {
      __syncthreads();
      const char* lKb = (const char*)&lK[buf][0];
      const char* lVb = (const char*)&lV[buf][0];
      const int ksmax = wid & 3;

      f32x4 st[4];
      #pragma unroll
      for (int ks = 0; ks < 4; ++ks){
        st[ks] = (f32x4){0.f, 0.f, 0.f, 0.f};
        if (ks <= ksmax){
          int row = ks * 16 + lr;
          bf16x8 k0 = *(const bf16x8*)(lKb + row * 128 + ((0 + g) ^ sw) * 16);
          bf16x8 k1 = *(const bf16x8*)(lKb + row * 128 + ((4 + g) ^ sw) * 16);
          st[ks] = __builtin_amdgcn_mfma_f32_16x16x32_bf16(k0, qf[0], st[ks], 0, 0, 0);
          st[ks] = __builtin_amdgcn_mfma_f32_16x16x32_bf16(k1, qf[1], st[ks], 0, 0, 0);
        }
      }

      #pragma unroll
      for (int ks = 0; ks < 4; ++ks){
        if (ks <= ksmax){
          float p[4];
          #pragma unroll
          for (int r = 0; r < 4; ++r){
            float v = st[ks][r];
            if (ks == ksmax && (4 * g + r > lr)) v = NEG;   // exp -> exact 0
            float e = __expf(v);
            p[r] = e; lsum += e;
          }
          union { unsigned u[2]; bf16x4 v; } pu;
          pu.u[0] = pack_bf16_trunc(p[0], p[1]);
          pu.u[1] = pack_bf16_trunc(p[2], p[3]);
          bf16x4 pa = pu.v;
          int chunk = ks * 2 + (g >> 1);
          #pragma unroll
          for (int dt = 0; dt < 4; ++dt){
            int row = dt * 16 + lr;
            bf16x4 vb = *(const bf16x4*)(lVb + row * 128 + (chunk ^ sw) * 16 + (g & 1) * 8);
            oacc[dt] = __builtin_amdgcn_mfma_f32_16x16x16bf16_1k(pa, vb, oacc[dt], 0, 0, 0);
          }
        }
      }
    }

    // ---- pass final: one cross-lane lsum reduce, normalize, write ----
    lsum += __shfl_xor(lsum, 16);
    lsum += __shfl_xor(lsum, 32);
    float inv[4];
    #pragma unroll
    for (int r = 0; r < 4; ++r) inv[r] = 1.0f / __shfl(lsum, 4 * g + r);
    float* obase = out + (size_t)(b * 2048 + q16) * 2048 + hq * 64;
    #pragma unroll
    for (int dt = 0; dt < 4; ++dt)
      #pragma unroll
      for (int r = 0; r < 4; ++r)
        obase[(size_t)(4 * g + r) * 2048 + dt * 16 + lr] = oacc[dt][r] * inv[r];
  }
}

// ---------------- launch ----------------
extern "C" void kernel_launch(void* const* d_in, const int* in_sizes, int n_in,
                              void* d_out, int out_size, void* d_ws, size_t ws_size,
                              hipStream_t stream) {
  const float* x  = (const float*)d_in[0];
  const float* Wq = (const float*)d_in[1];
  const float* Wk = (const float*)d_in[2];
  const float* Wv = (const float*)d_in[3];
  float* out = (float*)d_out;
  char* ws = (char*)d_ws;

  u16* Xb   = (u16*)(ws + 0);            // 16,777,216
  u16* Wt   = (u16*)(ws + 16777216);     // 12,582,912
  u16* Cb   = (u16*)(ws + 29360128);     // 25,165,824  (P0; Q cols final here)
  u16* Kr   = (u16*)(ws + 54525952);     //  4,194,304
  u16* Vt   = (u16*)(ws + 58720256);     //  4,194,304
  float* cosT = (float*)(ws + 62914560); //    262,144
  float* sinT = (float*)(ws + 63176704); //    262,144
  u16* P1   = (u16*)d_out;               // 25,165,824 <= 33,554,432 (attn overwrites after)

  k_prep<<<9984, 256, 0, stream>>>(x, Wq, Wk, Wv, Xb, Wt, cosT, sinT);
  k_gemm<<<dim3(32, 24, 2), 256, 0, stream>>>(Xb, Wt, Cb, P1);
  k_reduce<<<dim3(48, 64), 256, 0, stream>>>(Cb, P1, cosT, sinT, Kr, Vt);
  k_attn<<<dim3(16, 16, 2), 512, 0, stream>>>(Cb, Kr, Vt, cosT, sinT, out);
}

// Round 18
// 139.587 us; speedup vs baseline: 1.1132x; 1.0229x over previous
//
#include <hip/hip_runtime.h>

typedef unsigned short u16;
typedef __attribute__((ext_vector_type(4))) float f32x4;
typedef __attribute__((ext_vector_type(8))) short bf16x8;
typedef __attribute__((ext_vector_type(4))) short bf16x4;
typedef __attribute__((ext_vector_type(4))) unsigned short u16x4;
typedef __attribute__((ext_vector_type(2))) unsigned short u16x2;

#define DEV __device__ __forceinline__

DEV float bf2f(u16 u){ unsigned x = ((unsigned)u) << 16; return __builtin_bit_cast(float, x); }
DEV u16 f2bf(float f){
  unsigned x = __builtin_bit_cast(unsigned, f);
  x += 0x7fffu + ((x >> 16) & 1u);
  return (u16)(x >> 16);
}
// pack {lo,hi} f32 -> two bf16 (truncation) in one v_perm_b32
DEV unsigned pack_bf16_trunc(float lo, float hi){
  return __builtin_amdgcn_perm(__builtin_bit_cast(unsigned, hi),
                               __builtin_bit_cast(unsigned, lo), 0x07060302u);
}

DEV void gload_lds16(const void* g, void* l){
  __builtin_amdgcn_global_load_lds(
      (const __attribute__((address_space(1))) unsigned int*)(unsigned long long)g,
      (__attribute__((address_space(3))) unsigned int*)(unsigned)(unsigned long long)l,
      16, 0, 0);
}

// ---- merged prep: [0,8192) pack x; [8192,9728) pack W; [9728,9984) RoPE tables ----
__global__ void __launch_bounds__(256) k_prep(const float* __restrict__ x,
                                              const float* __restrict__ Wq,
                                              const float* __restrict__ Wk,
                                              const float* __restrict__ Wv,
                                              u16* __restrict__ xb,
                                              u16* __restrict__ Wt,
                                              float* __restrict__ cosT,
                                              float* __restrict__ sinT){
  __shared__ u16 tile[64][72];
  const int id = (int)blockIdx.x;
  if (id < 8192){
    int i = id * 256 + threadIdx.x;          // < 2097152
    f32x4 v = *(const f32x4*)&x[(size_t)i * 4];
    u16x4 o;
    o[0] = f2bf(v[0]); o[1] = f2bf(v[1]); o[2] = f2bf(v[2]); o[3] = f2bf(v[3]);
    *(u16x4*)&xb[(size_t)i * 4] = o;
  } else if (id < 9728){
    int idx = id - 8192;                     // 0..1535
    const int n0 = (idx % 48) * 64, k0 = (idx / 48) * 64;
    const float* src; int ncols, nloc;
    if (n0 < 2048)      { src = Wq; ncols = 2048; nloc = n0; }
    else if (n0 < 2560) { src = Wk; ncols = 512;  nloc = n0 - 2048; }
    else                { src = Wv; ncols = 512;  nloc = n0 - 2560; }
    #pragma unroll
    for (int i = 0; i < 4; ++i){
      int e = i * 1024 + threadIdx.x * 4;
      int r = e >> 6, c = e & 63;
      f32x4 v = *(const f32x4*)&src[(size_t)(k0 + r) * ncols + nloc + c];
      u16x4 o;
      o[0] = f2bf(v[0]); o[1] = f2bf(v[1]); o[2] = f2bf(v[2]); o[3] = f2bf(v[3]);
      *(u16x4*)&tile[r][c] = o;
    }
    __syncthreads();
    #pragma unroll
    for (int i = 0; i < 4; ++i){
      int e = i * 1024 + threadIdx.x * 4;
      int rn = e >> 6, ck = e & 63;
      u16x4 o;
      o[0] = tile[ck + 0][rn]; o[1] = tile[ck + 1][rn];
      o[2] = tile[ck + 2][rn]; o[3] = tile[ck + 3][rn];
      *(u16x4*)&Wt[(size_t)(n0 + rn) * 2048 + k0 + ck] = o;
    }
  } else {
    int i = (id - 9728) * 256 + threadIdx.x; // < 65536
    int pos = i >> 5, f = i & 31;
    float freq = expf(-(float)f * 0.28782313662425574f);  // 10000^(-f/32)
    float a = (float)pos * freq;
    cosT[i] = cosf(a);
    sinT[i] = sinf(a);
  }
}

// ---- GEMM, split-K=2, BK=64 single-buffer, EXPLICIT ADDRESS INDUCTION. ----
// 128x128 tile, 32KB LDS, 16 iterations. Staging pointers hoisted; per-iter += 128B
// (global_load_lds builtin inhibits LICM -> do it by hand). Swizzle chunk ^= row&7.
__global__ void __launch_bounds__(256) k_gemm(const u16* __restrict__ Xb,
                                              const u16* __restrict__ Wt,
                                              u16* __restrict__ P0,
                                              u16* __restrict__ P1){
  __shared__ u16 lA[128 * 64];
  __shared__ u16 lB[128 * 64];
  const int tid = threadIdx.x;
  const int wid = tid >> 6, lane = tid & 63;
  const int g = lane >> 4, lr = lane & 15;
  const int m0 = blockIdx.x * 128, n0 = blockIdx.y * 128;
  const int z = blockIdx.z;
  const int wm = wid >> 1, wn = wid & 1;

  f32x4 acc[4][4];
  #pragma unroll
  for (int i = 0; i < 4; ++i)
    #pragma unroll
    for (int j = 0; j < 4; ++j) acc[i][j] = (f32x4){0.f, 0.f, 0.f, 0.f};

  const char* gA = (const char*)Xb + (size_t)m0 * 4096 + z * 2048;  // K-half offset
  const char* gB = (const char*)Wt + (size_t)n0 * 4096 + z * 2048;

  // hoisted staging pointers (per-lane global src, wave-uniform LDS dest)
  const char* pa[4]; const char* pb[4];
  char* la[4]; char* lb[4];
  #pragma unroll
  for (int i = 0; i < 4; ++i){
    int idx = i * 256 + tid;                 // 1024 chunks of 16B per matrix
    int row = idx >> 3, cc = idx & 7;
    int sc = cc ^ (row & 7);                 // pre-swizzled source chunk
    pa[i] = gA + (size_t)row * 4096 + sc * 16;
    pb[i] = gB + (size_t)row * 4096 + sc * 16;
    la[i] = (char*)lA + i * 4096 + wid * 1024;
    lb[i] = (char*)lB + i * 4096 + wid * 1024;
  }

  for (int kt = 0; kt < 16; ++kt){
    #pragma unroll
    for (int i = 0; i < 4; ++i){
      gload_lds16(pa[i], la[i]);
      gload_lds16(pb[i], lb[i]);
    }
    __syncthreads();
    #pragma unroll
    for (int kk = 0; kk < 2; ++kk){
      bf16x8 a[4], b[4];
      #pragma unroll
      for (int i = 0; i < 4; ++i){
        int rowA = wm * 64 + i * 16 + lr;
        a[i] = *(const bf16x8*)&lA[rowA * 64 + (((kk << 2) | g) ^ (rowA & 7)) * 8];
      }
      #pragma unroll
      for (int j = 0; j < 4; ++j){
        int rowB = wn * 64 + j * 16 + lr;
        b[j] = *(const bf16x8*)&lB[rowB * 64 + (((kk << 2) | g) ^ (rowB & 7)) * 8];
      }
      #pragma unroll
      for (int i = 0; i < 4; ++i)
        #pragma unroll
        for (int j = 0; j < 4; ++j)
          acc[i][j] = __builtin_amdgcn_mfma_f32_16x16x32_bf16(a[i], b[j], acc[i][j], 0, 0, 0);
    }
    __syncthreads();
    #pragma unroll
    for (int i = 0; i < 4; ++i){ pa[i] += 128; pb[i] += 128; }
  }

  u16* P = z ? P1 : P0;
  #pragma unroll
  for (int i = 0; i < 4; ++i)
    #pragma unroll
    for (int j = 0; j < 4; ++j){
      int row = m0 + wm * 64 + i * 16 + g * 4;
      int col = n0 + wn * 64 + j * 16 + lr;
      #pragma unroll
      for (int r = 0; r < 4; ++r)
        P[(size_t)(row + r) * 3072 + col] = f2bf(acc[i][j][r]);
    }
}

// ---- reduce partials + epilogue: Q -> P0 in-place; K -> RoPE -> Kr; V -> transpose -> Vt ----
// grid (48 col-tiles, 64 row-tiles), 64x64 tile per block, 256 threads.
__global__ void __launch_bounds__(256) k_reduce(u16* __restrict__ P0,
                                                const u16* __restrict__ P1,
                                                const float* __restrict__ cosT,
                                                const float* __restrict__ sinT,
                                                u16* __restrict__ Kr,
                                                u16* __restrict__ Vt){
  __shared__ u16 tile[64][72];
  const int col0 = blockIdx.x * 64, row0 = blockIdx.y * 64;
  const int b = row0 >> 11, s0 = row0 & 2047;

  if (col0 < 2048){
    // ---- Q: sum -> P0 in place ----
    #pragma unroll
    for (int p = 0; p < 2; ++p){
      int it = p * 256 + threadIdx.x;
      int r = it >> 3, ch = it & 7;
      size_t off = (size_t)(row0 + r) * 3072 + col0 + ch * 8;
      bf16x8 a = *(const bf16x8*)&P0[off];
      bf16x8 c = *(const bf16x8*)&P1[off];
      bf16x8 o;
      #pragma unroll
      for (int j = 0; j < 8; ++j)
        o[j] = (short)f2bf(bf2f((u16)a[j]) + bf2f((u16)c[j]));
      *(bf16x8*)&P0[off] = o;
    }
  } else if (col0 < 2560){
    // ---- K: sum + RoPE -> Kr[b][hk][s][64] ----
    const int hk = (col0 - 2048) >> 6;
    u16* kout = Kr + (size_t)(b * 8 + hk) * 2048 * 64;
    #pragma unroll
    for (int p = 0; p < 2; ++p){
      int it = p * 256 + threadIdx.x;
      int r = it >> 3, ch = it & 7;
      int s = s0 + r;
      size_t off = (size_t)(row0 + r) * 3072 + col0 + ch * 8;
      bf16x8 a = *(const bf16x8*)&P0[off];
      bf16x8 c = *(const bf16x8*)&P1[off];
      float v[8];
      #pragma unroll
      for (int j = 0; j < 8; ++j) v[j] = bf2f((u16)a[j]) + bf2f((u16)c[j]);
      u16x4 o0, o1;
      #pragma unroll
      for (int j2 = 0; j2 < 4; ++j2){
        int fi = ch * 4 + j2;
        float cs = cosT[s * 32 + fi], sn = sinT[s * 32 + fi];
        float xe = v[2 * j2], xo = v[2 * j2 + 1];
        float oe = xe * cs - xo * sn;
        float oo = xe * sn + xo * cs;
        if (j2 < 2){ o0[2 * j2] = f2bf(oe); o0[2 * j2 + 1] = f2bf(oo); }
        else       { o1[2 * (j2 - 2)] = f2bf(oe); o1[2 * (j2 - 2) + 1] = f2bf(oo); }
      }
      *(u16x4*)&kout[(size_t)s * 64 + ch * 8] = o0;
      *(u16x4*)&kout[(size_t)s * 64 + ch * 8 + 4] = o1;
    }
  } else {
    // ---- V: sum -> LDS -> transposed -> Vt[b][hk][d][s] ----
    const int hk = (col0 - 2560) >> 6;
    #pragma unroll
    for (int p = 0; p < 2; ++p){
      int it = p * 256 + threadIdx.x;
      int r = it >> 3, ch = it & 7;
      size_t off = (size_t)(row0 + r) * 3072 + col0 + ch * 8;
      bf16x8 a = *(const bf16x8*)&P0[off];
      bf16x8 c = *(const bf16x8*)&P1[off];
      u16x4 t0, t1;
      #pragma unroll
      for (int j = 0; j < 4; ++j){
        t0[j] = f2bf(bf2f((u16)a[j]) + bf2f((u16)c[j]));
        t1[j] = f2bf(bf2f((u16)a[j + 4]) + bf2f((u16)c[j + 4]));
      }
      *(u16x4*)&tile[r][ch * 8] = t0;
      *(u16x4*)&tile[r][ch * 8 + 4] = t1;
    }
    __syncthreads();
    #pragma unroll
    for (int i = 0; i < 4; ++i){
      int e = i * 1024 + threadIdx.x * 4;
      int d = e >> 6, sc = e & 63;
      u16x4 o;
      o[0] = tile[sc + 0][d]; o[1] = tile[sc + 1][d];
      o[2] = tile[sc + 2][d]; o[3] = tile[sc + 3][d];
      *(u16x4*)&Vt[((size_t)(b * 8 + hk) * 64 + d) * 2048 + s0 + sc] = o;
    }
  }
}

// ---------------- Flash attention: causal GQA, KVBLK=64, qt-PAIRED uniform blocks ----------------
// R15-proven: 8 waves/block (512 thr), 2 heads/block, two passes qt = bx / 31-bx
// -> every block exactly 33 tile-units. Grid (16,16,2) = 512 blocks = 2/CU.
// Max-free softmax + deferred per-lane lsum; v_perm P-pack.
// Quarantined intrinsics (NaN, R3/R4/R6): exp2f builtin, cvt_pk asm, setprio.
__global__ void __launch_bounds__(512) k_attn(const u16* __restrict__ C,
                                              const u16* __restrict__ Kr,
                                              const u16* __restrict__ Vt,
                                              const float* __restrict__ cosT,
                                              const float* __restrict__ sinT,
                                              float* __restrict__ out){
  __shared__ u16 lK[2][4096];
  __shared__ u16 lV[2][4096];

  const int bx = (int)blockIdx.x;       // 0..15 -> qt pair {bx, 31-bx}
  const int by = (int)blockIdx.y;       // 0..15 -> hk = by>>1, head-pair = by&1
  const int b = (int)blockIdx.z;
  const int tid = threadIdx.x;
  const int wid = tid >> 6, lane = tid & 63;
  const int g = lane >> 4, lr = lane & 15;
  const int hk = by >> 1;
  const int hq = hk * 4 + (by & 1) * 2 + (wid >> 2);
  const float QSCL = 0.125f;            // fold 1/sqrt(64) into Q
  const float NEG = -60000.0f;          // masked-score sentinel (exp -> exact 0)
  const int sw = lr & 7;

  const char* kgbase = (const char*)(Kr + (size_t)(b * 8 + hk) * 2048 * 64);
  const char* vgbase = (const char*)(Vt + (size_t)(b * 8 + hk) * 64 * 2048);

  // STAGE tile tt: waves 0-3 stage K (512 chunks, 2/lane), waves 4-7 stage V.
  auto STAGE = [&](int tt, int bb){
    if (wid < 4){
      const char* kg = kgbase + (size_t)tt * 8192;     // 64 rows x 128B contiguous
      #pragma unroll
      for (int i = 0; i < 2; ++i){
        int dc = wid * 128 + i * 64 + lane;
        int row = dc >> 3, cc = dc & 7;
        int sc = cc ^ (row & 7);
        gload_lds16(kg + row * 128 + sc * 16,
                    (char*)&lK[bb][0] + wid * 2048 + i * 1024);
      }
    } else {
      const char* vg = vgbase + (size_t)tt * 128;      // 64B-window rows, 4096B stride
      int w2 = wid - 4;
      #pragma unroll
      for (int i = 0; i < 2; ++i){
        int dc = w2 * 128 + i * 64 + lane;
        int row = dc >> 3, cc = dc & 7;
        int sc = cc ^ (row & 7);
        gload_lds16(vg + (size_t)row * 4096 + sc * 16,
                    (char*)&lV[bb][0] + w2 * 2048 + i * 1024);
      }
    }
  };

  #pragma unroll 1
  for (int pass = 0; pass < 2; ++pass){
    const int qt = pass ? 31 - bx : bx;
    const int q16 = qt * 64 + (wid & 3) * 16;
    const int qrow = q16 + lr;

    // Q fragments (B-operand of 16x16x32: B[k=d][col=q]), RoPE + scale in-register
    bf16x8 qf[2];
    {
      const u16* qsrc = C + (size_t)(b * 2048 + qrow) * 3072 + hq * 64;
      #pragma unroll
      for (int c = 0; c < 2; ++c){
        bf16x8 v = *(const bf16x8*)&qsrc[c * 32 + g * 8];
        int i0 = c * 16 + g * 4;
        f32x4 cs = *(const f32x4*)&cosT[qrow * 32 + i0];
        f32x4 sn = *(const f32x4*)&sinT[qrow * 32 + i0];
        bf16x8 o;
        #pragma unroll
        for (int t = 0; t < 4; ++t){
          float xe = bf2f((u16)v[2 * t]), xo = bf2f((u16)v[2 * t + 1]);
          o[2 * t]     = (short)f2bf((xe * cs[t] - xo * sn[t]) * QSCL);
          o[2 * t + 1] = (short)f2bf((xe * sn[t] + xo * cs[t]) * QSCL);
        }
        qf[c] = o;
      }
    }

    f32x4 oacc[4];
    #pragma unroll
    for (int dt = 0; dt < 4; ++dt) oacc[dt] = (f32x4){0.f, 0.f, 0.f, 0.f};
    float lsum = 0.0f;                  // per-lane partial; reduced once at end

    __syncthreads();                    // protect LDS reuse across passes
    int buf = 0;
    STAGE(0, 0);

    // ============ hot loop: fully-unmasked tiles t = 0..qt-1 ============
    for (int t = 0; t < qt; ++t){
      __syncthreads();
      STAGE(t + 1, buf ^ 1);

      const char* lKb = (const char*)&lK[buf][0];
      const char* lVb = (const char*)&lV[buf][0];

      // ---- QK^T: S^T[kv][q], all 4 subtiles unmasked ----
      f32x4 st[4];
      #pragma unroll
      for (int ks = 0; ks < 4; ++ks){
        st[ks] = (f32x4){0.f, 0.f, 0.f, 0.f};
        int row = ks * 16 + lr;
        bf16x8 k0 = *(const bf16x8*)(lKb + row * 128 + ((0 + g) ^ sw) * 16);
        bf16x8 k1 = *(const bf16x8*)(lKb + row * 128 + ((4 + g) ^ sw) * 16);
        st[ks] = __builtin_amdgcn_mfma_f32_16x16x32_bf16(k0, qf[0], st[ks], 0, 0, 0);
        st[ks] = __builtin_amdgcn_mfma_f32_16x16x32_bf16(k1, qf[1], st[ks], 0, 0, 0);
      }

      // ---- max-free softmax: p = exp(s), per-lane lsum ----
      float p[4][4];
      #pragma unroll
      for (int ks = 0; ks < 4; ++ks){
        #pragma unroll
        for (int r = 0; r < 4; ++r){
          float e = __expf(st[ks][r]);
          p[ks][r] = e; lsum += e;
        }
      }

      // ---- PV: A[row=q=lr][k=kv=4g+j] = p, B from V^T LDS tile ----
      #pragma unroll
      for (int ks = 0; ks < 4; ++ks){
        union { unsigned u[2]; bf16x4 v; } pu;
        pu.u[0] = pack_bf16_trunc(p[ks][0], p[ks][1]);
        pu.u[1] = pack_bf16_trunc(p[ks][2], p[ks][3]);
        bf16x4 pa = pu.v;
        int chunk = ks * 2 + (g >> 1);
        #pragma unroll
        for (int dt = 0; dt < 4; ++dt){
          int row = dt * 16 + lr;
          bf16x4 vb = *(const bf16x4*)(lVb + row * 128 + (chunk ^ sw) * 16 + (g & 1) * 8);
          oacc[dt] = __builtin_amdgcn_mfma_f32_16x16x16bf16_1k(pa, vb, oacc[dt], 0, 0, 0);
        }
      }

      buf ^= 1;
    }

    // ============ diag tile t = qt (masked epilogue) ============
    {
      __syncthreads();
      const char* lKb = (const char*)&lK[buf][0];
      const char* lVb = (const char*)&lV[buf][0];
      const int ksmax = wid & 3;

      f32x4 st[4];
      #pragma unroll
      for (int ks = 0; ks < 4; ++ks){
        st[ks] = (f32x4){0.f, 0.f, 0.f, 0.f};
        if (ks <= ksmax){
          int row = ks * 16 + lr;
          bf16x8 k0 = *(const bf16x8*)(lKb + row * 128 + ((0 + g) ^ sw) * 16);
          bf16x8 k1 = *(const bf16x8*)(lKb + row * 128 + ((4 + g) ^ sw) * 16);
          st[ks] = __builtin_amdgcn_mfma_f32_16x16x32_bf16(k0, qf[0], st[ks], 0, 0, 0);
          st[ks] = __builtin_amdgcn_mfma_f32_16x16x32_bf16(k1, qf[1], st[ks], 0, 0, 0);
        }
      }

      #pragma unroll
      for (int ks = 0; ks < 4; ++ks){
        if (ks <= ksmax){
          float p[4];
          #pragma unroll
          for (int r = 0; r < 4; ++r){
            float v = st[ks][r];
            if (ks == ksmax && (4 * g + r > lr)) v = NEG;   // exp -> exact 0
            float e = __expf(v);
            p[r] = e; lsum += e;
          }
          union { unsigned u[2]; bf16x4 v; } pu;
          pu.u[0] = pack_bf16_trunc(p[0], p[1]);
          pu.u[1] = pack_bf16_trunc(p[2], p[3]);
          bf16x4 pa = pu.v;
          int chunk = ks * 2 + (g >> 1);
          #pragma unroll
          for (int dt = 0; dt < 4; ++dt){
            int row = dt * 16 + lr;
            bf16x4 vb = *(const bf16x4*)(lVb + row * 128 + (chunk ^ sw) * 16 + (g & 1) * 8);
            oacc[dt] = __builtin_amdgcn_mfma_f32_16x16x16bf16_1k(pa, vb, oacc[dt], 0, 0, 0);
          }
        }
      }
    }

    // ---- pass final: one cross-lane lsum reduce, normalize, write ----
    lsum += __shfl_xor(lsum, 16);
    lsum += __shfl_xor(lsum, 32);
    float inv[4];
    #pragma unroll
    for (int r = 0; r < 4; ++r) inv[r] = 1.0f / __shfl(lsum, 4 * g + r);
    float* obase = out + (size_t)(b * 2048 + q16) * 2048 + hq * 64;
    #pragma unroll
    for (int dt = 0; dt < 4; ++dt)
      #pragma unroll
      for (int r = 0; r < 4; ++r)
        obase[(size_t)(4 * g + r) * 2048 + dt * 16 + lr] = oacc[dt][r] * inv[r];
  }
}

// ---------------- launch ----------------
extern "C" void kernel_launch(void* const* d_in, const int* in_sizes, int n_in,
                              void* d_out, int out_size, void* d_ws, size_t ws_size,
                              hipStream_t stream) {
  const float* x  = (const float*)d_in[0];
  const float* Wq = (const float*)d_in[1];
  const float* Wk = (const float*)d_in[2];
  const float* Wv = (const float*)d_in[3];
  float* out = (float*)d_out;
  char* ws = (char*)d_ws;

  u16* Xb   = (u16*)(ws + 0);            // 16,777,216
  u16* Wt   = (u16*)(ws + 16777216);     // 12,582,912
  u16* Cb   = (u16*)(ws + 29360128);     // 25,165,824  (P0; Q cols final here)
  u16* Kr   = (u16*)(ws + 54525952);     //  4,194,304
  u16* Vt   = (u16*)(ws + 58720256);     //  4,194,304
  float* cosT = (float*)(ws + 62914560); //    262,144
  float* sinT = (float*)(ws + 63176704); //    262,144
  u16* P1   = (u16*)d_out;               // 25,165,824 <= 33,554,432 (attn overwrites after)

  k_prep<<<9984, 256, 0, stream>>>(x, Wq, Wk, Wv, Xb, Wt, cosT, sinT);
  k_gemm<<<dim3(32, 24, 2), 256, 0, stream>>>(Xb, Wt, Cb, P1);
  k_reduce<<<dim3(48, 64), 256, 0, stream>>>(Cb, P1, cosT, sinT, Kr, Vt);
  k_attn<<<dim3(16, 16, 2), 512, 0, stream>>>(Cb, Kr, Vt, cosT, sinT, out);
}